// Round 10
// baseline (504.475 us; speedup 1.0000x reference)
//
#include <hip/hip_runtime.h>
#include <hip/hip_bf16.h>

#define B_   8
#define LS_  1024
#define LT_  1024
#define D_   768
#define INV_REG 10.0f
#define EPS_ 1e-8f
#define AVAL (1.0f/1024.0f)
#define BVAL (1.0f/1024.0f)
#define NITER 10
#define SBLK 256           // sinkhorn grid: 256 blocks (1/CU)
#define BPB  (SBLK / 8)    // blocks per batch = 32
#define RPB  (LS_ / BPB)   // rows per block  = 32

typedef __attribute__((ext_vector_type(8))) short bf16x8;
typedef __attribute__((ext_vector_type(4))) float f32x4;

__device__ inline unsigned short f2bf(float f) {
    __hip_bfloat16 h = __float2bfloat16(f);
    return __builtin_bit_cast(unsigned short, h);
}
__device__ inline float bf2f(unsigned short u) {
    unsigned int x = ((unsigned int)u) << 16;
    return __builtin_bit_cast(float, x);
}

// ---------------- init: denS slab0 = AVAL-EPS (=> u0=1); zero denT slabs, part, bar, out
__global__ __launch_bounds__(256) void init_bufs(float* denS, float* denT, float* partialB,
                                                 int* bar, float* out) {
    int i = blockIdx.x * 256 + threadIdx.x;
    if (i < B_*LS_) denS[i] = AVAL - EPS_;
    if (i < NITER*B_*LT_) denT[i] = 0.0f;
    if (i < B_) partialB[i] = 0.0f;
    if (i < B_) bar[i] = 0;
    if (i == 0) out[0] = 0.0f;
}

// ---------------- prep: row sumsq + bf16 cast. 192 thr = 768/4; blocks 0..8191 student, rest teacher
__global__ __launch_bounds__(192) void prep_rows(const float* __restrict__ S, const float* __restrict__ T,
                                                 unsigned short* __restrict__ sbf, unsigned short* __restrict__ tbf,
                                                 float* __restrict__ sqS, float* __restrict__ sqT) {
    int bid = blockIdx.x;
    bool teach = bid >= B_*LS_;
    int row = teach ? bid - B_*LS_ : bid;
    const float* src = (teach ? T : S) + (size_t)row * D_;
    unsigned short* dst = (teach ? tbf : sbf) + (size_t)row * D_;
    int t = threadIdx.x;
    float4 v = *(const float4*)(src + t * 4);
    float ss = v.x*v.x + v.y*v.y + v.z*v.z + v.w*v.w;
    ushort4 o;
    o.x = f2bf(v.x); o.y = f2bf(v.y); o.z = f2bf(v.z); o.w = f2bf(v.w);
    *(ushort4*)(dst + t * 4) = o;
    for (int off = 32; off; off >>= 1) ss += __shfl_down(ss, off);
    __shared__ float red[3];
    int wid = t >> 6, lane = t & 63;
    if (lane == 0) red[wid] = ss;
    __syncthreads();
    if (t == 0) (teach ? sqT : sqS)[row] = red[0] + red[1] + red[2];
}

// ---------------- GEMM + cdist epilogue -> Kb = bf16(exp(-10C)), Cbm = bf16(C)
__device__ inline void gload_lds16(const void* g, void* l) {
    __builtin_amdgcn_global_load_lds((const __attribute__((address_space(1))) void*)g,
                                     (__attribute__((address_space(3))) void*)l, 16, 0, 0);
}

__global__ __launch_bounds__(256) void gemm_cdist(const unsigned short* __restrict__ S,
                                                  const unsigned short* __restrict__ T,
                                                  const float* __restrict__ sqS, const float* __restrict__ sqT,
                                                  unsigned short* __restrict__ Kb,
                                                  unsigned short* __restrict__ Cbm) {
    __shared__ unsigned short As[128 * 32];
    __shared__ unsigned short Bs[128 * 32];
    const int bid  = blockIdx.x;
    const int b    = bid & 7;
    const int tile = bid >> 3;
    const int brow = (tile >> 3) * 128;
    const int bcol = (tile & 7) * 128;
    const int tid  = threadIdx.x;
    const int wid  = tid >> 6, lane = tid & 63;
    const int wr = wid >> 1, wc = wid & 1;            // 2x2 waves, each 64x64
    const unsigned short* Sg = S + ((size_t)b * LS_ + brow) * D_;
    const unsigned short* Tg = T + ((size_t)b * LT_ + bcol) * D_;

    f32x4 acc[4][4] = {};
    const int r16 = lane & 15, kg = lane >> 4;

    for (int k0 = 0; k0 < D_; k0 += 32) {
        #pragma unroll
        for (int j = 0; j < 2; ++j) {
            int lin = j * 256 + tid;                  // 16B chunk id (512 per tile)
            int row = lin >> 2, c8 = (lin & 3) * 8;
            unsigned short* la = As + (size_t)(j * 256 + wid * 64) * 8;  // wave-uniform base
            unsigned short* lb = Bs + (size_t)(j * 256 + wid * 64) * 8;
            gload_lds16(Sg + (size_t)row * D_ + k0 + c8, la);
            gload_lds16(Tg + (size_t)row * D_ + k0 + c8, lb);
        }
        __syncthreads();
        bf16x8 af[4], bfr[4];
        #pragma unroll
        for (int f = 0; f < 4; ++f) {
            af[f]  = *(const bf16x8*)(As + (wr * 64 + f * 16 + r16) * 32 + kg * 8);
            bfr[f] = *(const bf16x8*)(Bs + (wc * 64 + f * 16 + r16) * 32 + kg * 8);
        }
        #pragma unroll
        for (int i = 0; i < 4; ++i)
            #pragma unroll
            for (int j = 0; j < 4; ++j)
                acc[i][j] = __builtin_amdgcn_mfma_f32_16x16x32_bf16(af[i], bfr[j], acc[i][j], 0, 0, 0);
        __syncthreads();
    }

    // epilogue: C/D map col=lane&15, row=(lane>>4)*4+reg
    #pragma unroll
    for (int i = 0; i < 4; ++i) {
        int gr0 = brow + wr * 64 + i * 16 + (lane >> 4) * 4;
        #pragma unroll
        for (int j = 0; j < 4; ++j) {
            int gc = bcol + wc * 64 + j * 16 + (lane & 15);
            float st = sqT[b * LT_ + gc];
            #pragma unroll
            for (int r = 0; r < 4; ++r) {
                float ss = sqS[b * LS_ + gr0 + r];
                float d2 = ss + st - 2.0f * acc[i][j][r];
                float c  = sqrtf(fmaxf(d2, 0.0f));
                size_t idx = ((size_t)b << 20) + (size_t)(gr0 + r) * LT_ + gc;
                Kb[idx]  = f2bf(__expf(-INV_REG * c));
                Cbm[idx] = f2bf(c);
            }
        }
    }
}

// ---------------- per-batch device barrier (cooperative launch guarantees co-residency)
__device__ inline void batch_barrier(int* bar, int b, int target) {
    __syncthreads();                       // drains this block's vmem (incl. atomics) before arrival
    if (threadIdx.x == 0) {
        __hip_atomic_fetch_add(&bar[b], 1, __ATOMIC_RELEASE, __HIP_MEMORY_SCOPE_AGENT);
        while (__hip_atomic_load(&bar[b], __ATOMIC_ACQUIRE, __HIP_MEMORY_SCOPE_AGENT) < target) {
            __builtin_amdgcn_s_sleep(4);
        }
        __threadfence();
    }
    __syncthreads();
}

// ---------------- fused Sinkhorn: 10 iters + final loss, single launch
// grid 256 blocks x 256 thr; b = bid&7 (XCD pin), 32 blocks/batch x 32 rows each.
// denS is BLOCK-LOCAL (U writes exactly the rows this block's V reads) -> 1 barrier/iter.
__global__ __launch_bounds__(256) void sinkhorn_fused(
        const unsigned short* __restrict__ Kb, const unsigned short* __restrict__ Cbm,
        float* __restrict__ denS, float* __restrict__ denT,
        float* __restrict__ part, int* __restrict__ bar) {
    const int bid = blockIdx.x;
    const int b = bid & 7, blk = bid >> 3;
    const int s0 = blk * RPB;
    const int tid = threadIdx.x;
    const int w = tid >> 6, lane = tid & 63;
    const unsigned short* Kbat = Kb + ((size_t)b << 20);
    const int c4 = lane * 4;                         // lane's 4-col base within a 256-col group

    for (int it = 0; it < NITER; ++it) {
        const float* dS = denS + (size_t)it * (B_*LS_) + b * LS_;
        float* dT = denT + (size_t)it * (B_*LT_) + b * LT_;
        // ---- V: denT[t] += sum_s K[s][t] * u_s   (thread owns cols 4*tid..4*tid+3)
        float a0 = 0.f, a1 = 0.f, a2 = 0.f, a3 = 0.f;
        #pragma unroll 8
        for (int r = 0; r < RPB; ++r) {
            int s = s0 + r;
            float u = AVAL / (dS[s] + EPS_);         // broadcast load
            ushort4 k4 = *(const ushort4*)(Kbat + ((size_t)s << 10) + tid * 4);
            a0 += bf2f(k4.x) * u;
            a1 += bf2f(k4.y) * u;
            a2 += bf2f(k4.z) * u;
            a3 += bf2f(k4.w) * u;
        }
        atomicAdd(&dT[tid * 4 + 0], a0);
        atomicAdd(&dT[tid * 4 + 1], a1);
        atomicAdd(&dT[tid * 4 + 2], a2);
        atomicAdd(&dT[tid * 4 + 3], a3);
        batch_barrier(bar, b, (it + 1) * BPB);       // denT complete for batch b
        // ---- v in registers: lane owns cols q*256 + lane*4 + c  (float4 loads)
        float4 vq[4];
        #pragma unroll
        for (int q = 0; q < 4; ++q) vq[q] = *(const float4*)(dT + q * 256 + c4);
        #pragma unroll
        for (int q = 0; q < 4; ++q) {
            vq[q].x = BVAL / (vq[q].x + EPS_);
            vq[q].y = BVAL / (vq[q].y + EPS_);
            vq[q].z = BVAL / (vq[q].z + EPS_);
            vq[q].w = BVAL / (vq[q].w + EPS_);
        }
        // ---- U: denS_next[s] = sum_t K[s][t] * v_t  (4 waves x 8 rows, ushort4 loads)
        float* dSn = denS + (size_t)(it + 1) * (B_*LS_) + b * LS_;
        for (int rr = 0; rr < RPB / 4; ++rr) {
            int s = s0 + w * (RPB / 4) + rr;
            const unsigned short* Kr = Kbat + ((size_t)s << 10);
            float acc = 0.f;
            #pragma unroll
            for (int q = 0; q < 4; ++q) {
                ushort4 k4 = *(const ushort4*)(Kr + q * 256 + c4);
                acc += bf2f(k4.x) * vq[q].x + bf2f(k4.y) * vq[q].y
                     + bf2f(k4.z) * vq[q].z + bf2f(k4.w) * vq[q].w;
            }
            for (int off = 32; off; off >>= 1) acc += __shfl_down(acc, off);
            if (lane == 0) dSn[s] = acc;
        }
        __syncthreads();                             // intra-block visibility of dSn for next V
    }

    // ---- final: loss_b = sum_s u_s * sum_t K*C*v_t  (u from denS[10], v from denT[9])
    const float* dSf = denS + (size_t)NITER * (B_*LS_) + b * LS_;
    const float* dTf = denT + (size_t)(NITER - 1) * (B_*LT_) + b * LT_;
    const unsigned short* Cbat = Cbm + ((size_t)b << 20);
    float4 vq[4];
    #pragma unroll
    for (int q = 0; q < 4; ++q) vq[q] = *(const float4*)(dTf + q * 256 + c4);
    #pragma unroll
    for (int q = 0; q < 4; ++q) {
        vq[q].x = BVAL / (vq[q].x + EPS_);
        vq[q].y = BVAL / (vq[q].y + EPS_);
        vq[q].z = BVAL / (vq[q].z + EPS_);
        vq[q].w = BVAL / (vq[q].w + EPS_);
    }
    float bacc = 0.f;
    for (int rr = 0; rr < RPB / 4; ++rr) {
        int s = s0 + w * (RPB / 4) + rr;
        const unsigned short* Kr = Kbat + ((size_t)s << 10);
        const unsigned short* Cr = Cbat + ((size_t)s << 10);
        float acc = 0.f;
        #pragma unroll
        for (int q = 0; q < 4; ++q) {
            ushort4 k4 = *(const ushort4*)(Kr + q * 256 + c4);
            ushort4 cc = *(const ushort4*)(Cr + q * 256 + c4);
            acc += bf2f(k4.x) * bf2f(cc.x) * vq[q].x + bf2f(k4.y) * bf2f(cc.y) * vq[q].y
                 + bf2f(k4.z) * bf2f(cc.z) * vq[q].z + bf2f(k4.w) * bf2f(cc.w) * vq[q].w;
        }
        for (int off = 32; off; off >>= 1) acc += __shfl_down(acc, off);
        if (lane == 0) bacc += acc * (AVAL / (dSf[s] + EPS_));
    }
    __shared__ float red[4];
    if (lane == 0) red[w] = bacc;
    __syncthreads();
    if (tid == 0) atomicAdd(&part[b], red[0] + red[1] + red[2] + red[3]);
}

__global__ void finalize(const float* __restrict__ partialB, float* __restrict__ out) {
    if (threadIdx.x == 0) {
        float s = 0.0f;
        for (int i = 0; i < B_; ++i) s += partialB[i];
        out[0] = s / (float)B_;
    }
}

extern "C" void kernel_launch(void* const* d_in, const int* in_sizes, int n_in,
                              void* d_out, int out_size, void* d_ws, size_t ws_size,
                              hipStream_t stream) {
    const float* S = (const float*)d_in[0];
    const float* T = (const float*)d_in[1];
    float* out = (float*)d_out;
    char* ws = (char*)d_ws;

    // workspace layout (bytes); total ~59.6 MB
    const size_t offKb   = 0;                                    // 8*1024*1024 bf16 = 16777216
    const size_t offCb   = offKb   + (size_t)B_*LS_*LT_*2;       // 16777216
    const size_t offSbf  = offCb   + (size_t)B_*LS_*LT_*2;       // 12582912
    const size_t offTbf  = offSbf  + (size_t)B_*LS_*D_*2;        // 12582912
    const size_t offSqS  = offTbf  + (size_t)B_*LT_*D_*2;
    const size_t offSqT  = offSqS  + (size_t)B_*LS_*4;
    const size_t offDenS = offSqT  + (size_t)B_*LT_*4;           // (NITER+1) slabs
    const size_t offDenT = offDenS + (size_t)(NITER+1)*B_*LS_*4; // NITER slabs
    const size_t offPart = offDenT + (size_t)NITER*B_*LT_*4;
    const size_t offBar  = offPart + 64;
    const size_t need    = offBar + 64;
    if (ws_size < need) return;  // fail loudly rather than corrupt

    unsigned short* Kb  = (unsigned short*)(ws + offKb);
    unsigned short* Cbm = (unsigned short*)(ws + offCb);
    unsigned short* sbf = (unsigned short*)(ws + offSbf);
    unsigned short* tbf = (unsigned short*)(ws + offTbf);
    float* sqS  = (float*)(ws + offSqS);
    float* sqT  = (float*)(ws + offSqT);
    float* denS = (float*)(ws + offDenS);
    float* denT = (float*)(ws + offDenT);
    float* part = (float*)(ws + offPart);
    int*   bar  = (int*)(ws + offBar);

    int initN = NITER * B_ * LT_;   // largest init span
    init_bufs<<<(initN + 255) / 256, 256, 0, stream>>>(denS, denT, part, bar, out);
    prep_rows<<<2 * B_ * LS_, 192, 0, stream>>>(S, T, sbf, tbf, sqS, sqT);
    gemm_cdist<<<512, 256, 0, stream>>>(sbf, tbf, sqS, sqT, Kb, Cbm);

    void* args[] = { (void*)&Kb, (void*)&Cbm, (void*)&denS, (void*)&denT, (void*)&part, (void*)&bar };
    hipLaunchCooperativeKernel((const void*)sinkhorn_fused, dim3(SBLK), dim3(256), args, 0, stream);

    finalize<<<1, 64, 0, stream>>>(part, out);
}

// Round 11
// 442.334 us; speedup vs baseline: 1.1405x; 1.1405x over previous
//
#include <hip/hip_runtime.h>
#include <hip/hip_bf16.h>

#define B_   8
#define LS_  1024
#define LT_  1024
#define D_   768
#define INV_REG 10.0f
#define EPS_ 1e-8f
#define AVAL (1.0f/1024.0f)
#define BVAL (1.0f/1024.0f)
#define NITER 10
#define SBLK 256           // sinkhorn grid: 256 blocks (1/CU)
#define BPB  (SBLK / 8)    // blocks per batch = 32
#define RPB  (LS_ / BPB)   // rows per block  = 32

typedef __attribute__((ext_vector_type(8))) short bf16x8;
typedef __attribute__((ext_vector_type(4))) float f32x4;

__device__ inline unsigned short f2bf(float f) {
    __hip_bfloat16 h = __float2bfloat16(f);
    return __builtin_bit_cast(unsigned short, h);
}
__device__ inline float bf2f(unsigned short u) {
    unsigned int x = ((unsigned int)u) << 16;
    return __builtin_bit_cast(float, x);
}
// agent-scope (device-coherent) slab access: visible across XCDs regardless of block placement
__device__ inline void slab_store(float* p, float v) {
    __hip_atomic_store(p, v, __ATOMIC_RELAXED, __HIP_MEMORY_SCOPE_AGENT);
}
__device__ inline float slab_load(const float* p) {
    return __hip_atomic_load(p, __ATOMIC_RELAXED, __HIP_MEMORY_SCOPE_AGENT);
}

// ---------------- init: denS slab0 = AVAL-EPS (=> u0=1); zero part, bar(padded), out
__global__ __launch_bounds__(256) void init_bufs(float* denS, float* partialB, int* bar, float* out) {
    int i = blockIdx.x * 256 + threadIdx.x;
    if (i < B_*LS_) denS[i] = AVAL - EPS_;
    if (i < B_) partialB[i] = 0.0f;
    if (i < B_ * 16) bar[i] = 0;               // 8 counters, 64B apart
    if (i == 0) out[0] = 0.0f;
}

// ---------------- prep: row sumsq + bf16 cast. 192 thr = 768/4; blocks 0..8191 student, rest teacher
__global__ __launch_bounds__(192) void prep_rows(const float* __restrict__ S, const float* __restrict__ T,
                                                 unsigned short* __restrict__ sbf, unsigned short* __restrict__ tbf,
                                                 float* __restrict__ sqS, float* __restrict__ sqT) {
    int bid = blockIdx.x;
    bool teach = bid >= B_*LS_;
    int row = teach ? bid - B_*LS_ : bid;
    const float* src = (teach ? T : S) + (size_t)row * D_;
    unsigned short* dst = (teach ? tbf : sbf) + (size_t)row * D_;
    int t = threadIdx.x;
    float4 v = *(const float4*)(src + t * 4);
    float ss = v.x*v.x + v.y*v.y + v.z*v.z + v.w*v.w;
    ushort4 o;
    o.x = f2bf(v.x); o.y = f2bf(v.y); o.z = f2bf(v.z); o.w = f2bf(v.w);
    *(ushort4*)(dst + t * 4) = o;
    for (int off = 32; off; off >>= 1) ss += __shfl_down(ss, off);
    __shared__ float red[3];
    int wid = t >> 6, lane = t & 63;
    if (lane == 0) red[wid] = ss;
    __syncthreads();
    if (t == 0) (teach ? sqT : sqS)[row] = red[0] + red[1] + red[2];
}

// ---------------- GEMM + cdist epilogue -> Kb = bf16(exp(-10C)), Cbm = bf16(C)
__device__ inline void gload_lds16(const void* g, void* l) {
    __builtin_amdgcn_global_load_lds((const __attribute__((address_space(1))) void*)g,
                                     (__attribute__((address_space(3))) void*)l, 16, 0, 0);
}

__global__ __launch_bounds__(256) void gemm_cdist(const unsigned short* __restrict__ S,
                                                  const unsigned short* __restrict__ T,
                                                  const float* __restrict__ sqS, const float* __restrict__ sqT,
                                                  unsigned short* __restrict__ Kb,
                                                  unsigned short* __restrict__ Cbm) {
    __shared__ unsigned short As[128 * 32];
    __shared__ unsigned short Bs[128 * 32];
    const int bid  = blockIdx.x;
    const int b    = bid & 7;
    const int tile = bid >> 3;
    const int brow = (tile >> 3) * 128;
    const int bcol = (tile & 7) * 128;
    const int tid  = threadIdx.x;
    const int wid  = tid >> 6, lane = tid & 63;
    const int wr = wid >> 1, wc = wid & 1;            // 2x2 waves, each 64x64
    const unsigned short* Sg = S + ((size_t)b * LS_ + brow) * D_;
    const unsigned short* Tg = T + ((size_t)b * LT_ + bcol) * D_;

    f32x4 acc[4][4] = {};
    const int r16 = lane & 15, kg = lane >> 4;

    for (int k0 = 0; k0 < D_; k0 += 32) {
        #pragma unroll
        for (int j = 0; j < 2; ++j) {
            int lin = j * 256 + tid;                  // 16B chunk id (512 per tile)
            int row = lin >> 2, c8 = (lin & 3) * 8;
            unsigned short* la = As + (size_t)(j * 256 + wid * 64) * 8;  // wave-uniform base
            unsigned short* lb = Bs + (size_t)(j * 256 + wid * 64) * 8;
            gload_lds16(Sg + (size_t)row * D_ + k0 + c8, la);
            gload_lds16(Tg + (size_t)row * D_ + k0 + c8, lb);
        }
        __syncthreads();
        bf16x8 af[4], bfr[4];
        #pragma unroll
        for (int f = 0; f < 4; ++f) {
            af[f]  = *(const bf16x8*)(As + (wr * 64 + f * 16 + r16) * 32 + kg * 8);
            bfr[f] = *(const bf16x8*)(Bs + (wc * 64 + f * 16 + r16) * 32 + kg * 8);
        }
        #pragma unroll
        for (int i = 0; i < 4; ++i)
            #pragma unroll
            for (int j = 0; j < 4; ++j)
                acc[i][j] = __builtin_amdgcn_mfma_f32_16x16x32_bf16(af[i], bfr[j], acc[i][j], 0, 0, 0);
        __syncthreads();
    }

    // epilogue: C/D map col=lane&15, row=(lane>>4)*4+reg
    #pragma unroll
    for (int i = 0; i < 4; ++i) {
        int gr0 = brow + wr * 64 + i * 16 + (lane >> 4) * 4;
        #pragma unroll
        for (int j = 0; j < 4; ++j) {
            int gc = bcol + wc * 64 + j * 16 + (lane & 15);
            float st = sqT[b * LT_ + gc];
            #pragma unroll
            for (int r = 0; r < 4; ++r) {
                float ss = sqS[b * LS_ + gr0 + r];
                float d2 = ss + st - 2.0f * acc[i][j][r];
                float c  = sqrtf(fmaxf(d2, 0.0f));
                size_t idx = ((size_t)b << 20) + (size_t)(gr0 + r) * LT_ + gc;
                Kb[idx]  = f2bf(__expf(-INV_REG * c));
                Cbm[idx] = f2bf(c);
            }
        }
    }
}

// ---------------- per-batch device barrier (padded counters; coop launch = co-resident)
__device__ inline void batch_barrier(int* bar, int b, int target) {
    __syncthreads();                       // drains this block's vmem (incl. sc1 stores) before arrival
    if (threadIdx.x == 0) {
        __hip_atomic_fetch_add(&bar[b * 16], 1, __ATOMIC_RELEASE, __HIP_MEMORY_SCOPE_AGENT);
        while (__hip_atomic_load(&bar[b * 16], __ATOMIC_ACQUIRE, __HIP_MEMORY_SCOPE_AGENT) < target) {
            __builtin_amdgcn_s_sleep(4);
        }
        __threadfence();
    }
    __syncthreads();
}

// ---------------- fused Sinkhorn: 10 iters + final loss, single launch, NO global atomics in loop
// grid 256 x 256thr; b = bid&7, 32 blocks/batch x 32 rows. denS block-local -> 1 barrier/iter.
// denT via per-block slabs (parity double-buffered) + wave-split reduce through LDS.
__global__ __launch_bounds__(256) void sinkhorn_fused(
        const unsigned short* __restrict__ Kb, const unsigned short* __restrict__ Cbm,
        float* __restrict__ denS, float* __restrict__ denTp,
        float* __restrict__ part, int* __restrict__ bar) {
    const int bid = blockIdx.x;
    const int b = bid & 7, blk = bid >> 3;
    const int s0 = blk * RPB;
    const int tid = threadIdx.x;
    const int w = tid >> 6, lane = tid & 63;
    const unsigned short* Kbat = Kb + ((size_t)b << 20);
    const int c4 = lane * 4;                         // lane's 4-col base within a 256-col group
    __shared__ float wred[4][1024];                  // 16 KB wave partial sums
    float4 vq[4];                                    // survives loop: final phase uses iter-9 v

    for (int it = 0; it < NITER; ++it) {
        const float* dS = denS + (size_t)it * (B_*LS_) + b * LS_;
        // ---- V: slab[t] = sum_s K[s][t] * u_s  (thread owns cols 4*tid..4*tid+3)
        float a0 = 0.f, a1 = 0.f, a2 = 0.f, a3 = 0.f;
        #pragma unroll 8
        for (int r = 0; r < RPB; ++r) {
            int s = s0 + r;
            float u = AVAL / (dS[s] + EPS_);         // broadcast load (block-local data)
            ushort4 k4 = *(const ushort4*)(Kbat + ((size_t)s << 10) + tid * 4);
            a0 += bf2f(k4.x) * u;
            a1 += bf2f(k4.y) * u;
            a2 += bf2f(k4.z) * u;
            a3 += bf2f(k4.w) * u;
        }
        float* slab = denTp + ((size_t)((it & 1) * SBLK + bid) << 10);
        slab_store(slab + tid * 4 + 0, a0);
        slab_store(slab + tid * 4 + 1, a1);
        slab_store(slab + tid * 4 + 2, a2);
        slab_store(slab + tid * 4 + 3, a3);
        batch_barrier(bar, b, (it + 1) * BPB);       // all slabs of batch b complete
        // ---- reduce 32 slabs: wave w sums slabs k=w*8..w*8+7 into wred[w]
        const float* base = denTp + ((size_t)((it & 1) * SBLK + b) << 10);
        #pragma unroll
        for (int q = 0; q < 4; ++q) {
            float rx = 0.f, ry = 0.f, rz = 0.f, rw = 0.f;
            #pragma unroll
            for (int p = 0; p < 8; ++p) {
                const float* sp = base + ((size_t)(8 * (w * 8 + p)) << 10) + q * 256 + c4;
                rx += slab_load(sp + 0);
                ry += slab_load(sp + 1);
                rz += slab_load(sp + 2);
                rw += slab_load(sp + 3);
            }
            *(float4*)&wred[w][q * 256 + c4] = make_float4(rx, ry, rz, rw);
        }
        __syncthreads();
        #pragma unroll
        for (int q = 0; q < 4; ++q) {
            float4 p0 = *(const float4*)&wred[0][q * 256 + c4];
            float4 p1 = *(const float4*)&wred[1][q * 256 + c4];
            float4 p2 = *(const float4*)&wred[2][q * 256 + c4];
            float4 p3 = *(const float4*)&wred[3][q * 256 + c4];
            vq[q].x = BVAL / (p0.x + p1.x + p2.x + p3.x + EPS_);
            vq[q].y = BVAL / (p0.y + p1.y + p2.y + p3.y + EPS_);
            vq[q].z = BVAL / (p0.z + p1.z + p2.z + p3.z + EPS_);
            vq[q].w = BVAL / (p0.w + p1.w + p2.w + p3.w + EPS_);
        }
        // ---- U: denS_next[s] = sum_t K[s][t] * v_t  (4 waves x 8 rows)
        float* dSn = denS + (size_t)(it + 1) * (B_*LS_) + b * LS_;
        for (int rr = 0; rr < RPB / 4; ++rr) {
            int s = s0 + w * (RPB / 4) + rr;
            const unsigned short* Kr = Kbat + ((size_t)s << 10);
            float acc = 0.f;
            #pragma unroll
            for (int q = 0; q < 4; ++q) {
                ushort4 k4 = *(const ushort4*)(Kr + q * 256 + c4);
                acc += bf2f(k4.x) * vq[q].x + bf2f(k4.y) * vq[q].y
                     + bf2f(k4.z) * vq[q].z + bf2f(k4.w) * vq[q].w;
            }
            for (int off = 32; off; off >>= 1) acc += __shfl_down(acc, off);
            if (lane == 0) dSn[s] = acc;
        }
        __syncthreads();   // dSn (cross-wave) + wred WAR protection for next iter
    }

    // ---- final: loss_b = sum_s u_s * sum_t K*C*v_t ; vq still holds iter-9 v
    const float* dSf = denS + (size_t)NITER * (B_*LS_) + b * LS_;
    const unsigned short* Cbat = Cbm + ((size_t)b << 20);
    float bacc = 0.f;
    for (int rr = 0; rr < RPB / 4; ++rr) {
        int s = s0 + w * (RPB / 4) + rr;
        const unsigned short* Kr = Kbat + ((size_t)s << 10);
        const unsigned short* Cr = Cbat + ((size_t)s << 10);
        float acc = 0.f;
        #pragma unroll
        for (int q = 0; q < 4; ++q) {
            ushort4 k4 = *(const ushort4*)(Kr + q * 256 + c4);
            ushort4 cc = *(const ushort4*)(Cr + q * 256 + c4);
            acc += bf2f(k4.x) * bf2f(cc.x) * vq[q].x + bf2f(k4.y) * bf2f(cc.y) * vq[q].y
                 + bf2f(k4.z) * bf2f(cc.z) * vq[q].z + bf2f(k4.w) * bf2f(cc.w) * vq[q].w;
        }
        for (int off = 32; off; off >>= 1) acc += __shfl_down(acc, off);
        if (lane == 0) bacc += acc * (AVAL / (dSf[s] + EPS_));
    }
    __shared__ float red[4];
    if (lane == 0) red[w] = bacc;
    __syncthreads();
    if (tid == 0) atomicAdd(&part[b], red[0] + red[1] + red[2] + red[3]);
}

__global__ void finalize(const float* __restrict__ partialB, float* __restrict__ out) {
    if (threadIdx.x == 0) {
        float s = 0.0f;
        for (int i = 0; i < B_; ++i) s += partialB[i];
        out[0] = s / (float)B_;
    }
}

extern "C" void kernel_launch(void* const* d_in, const int* in_sizes, int n_in,
                              void* d_out, int out_size, void* d_ws, size_t ws_size,
                              hipStream_t stream) {
    const float* S = (const float*)d_in[0];
    const float* T = (const float*)d_in[1];
    float* out = (float*)d_out;
    char* ws = (char*)d_ws;

    // workspace layout (bytes); total ~61 MB
    const size_t offKb   = 0;                                    // 16777216
    const size_t offCb   = offKb   + (size_t)B_*LS_*LT_*2;       // 16777216
    const size_t offSbf  = offCb   + (size_t)B_*LS_*LT_*2;       // 12582912
    const size_t offTbf  = offSbf  + (size_t)B_*LS_*D_*2;        // 12582912
    const size_t offSqS  = offTbf  + (size_t)B_*LT_*D_*2;
    const size_t offSqT  = offSqS  + (size_t)B_*LS_*4;
    const size_t offDenS = offSqT  + (size_t)B_*LT_*4;           // (NITER+1) slabs of 32KB
    const size_t offDenTp= offDenS + (size_t)(NITER+1)*B_*LS_*4; // 2 x 256 x 1024 f32 = 2MB
    const size_t offPart = offDenTp+ (size_t)2*SBLK*LT_*4;
    const size_t offBar  = offPart + 64;
    const size_t need    = offBar + 1024;
    if (ws_size < need) return;  // fail loudly rather than corrupt

    unsigned short* Kb  = (unsigned short*)(ws + offKb);
    unsigned short* Cbm = (unsigned short*)(ws + offCb);
    unsigned short* sbf = (unsigned short*)(ws + offSbf);
    unsigned short* tbf = (unsigned short*)(ws + offTbf);
    float* sqS  = (float*)(ws + offSqS);
    float* sqT  = (float*)(ws + offSqT);
    float* denS = (float*)(ws + offDenS);
    float* denTp= (float*)(ws + offDenTp);
    float* part = (float*)(ws + offPart);
    int*   bar  = (int*)(ws + offBar);

    init_bufs<<<(B_*LS_ + 255) / 256, 256, 0, stream>>>(denS, part, bar, out);
    prep_rows<<<2 * B_ * LS_, 192, 0, stream>>>(S, T, sbf, tbf, sqS, sqT);
    gemm_cdist<<<512, 256, 0, stream>>>(sbf, tbf, sqS, sqT, Kb, Cbm);

    void* args[] = { (void*)&Kb, (void*)&Cbm, (void*)&denS, (void*)&denTp, (void*)&part, (void*)&bar };
    hipLaunchCooperativeKernel((const void*)sinkhorn_fused, dim3(SBLK), dim3(256), args, 0, stream);

    finalize<<<1, 64, 0, stream>>>(part, out);
}

// Round 12
// 211.618 us; speedup vs baseline: 2.3839x; 2.0903x over previous
//
#include <hip/hip_runtime.h>
#include <hip/hip_bf16.h>

#define B_   8
#define LS_  1024
#define LT_  1024
#define D_   768
#define INV_REG 10.0f
#define EPS_ 1e-8f
#define AVAL (1.0f/1024.0f)
#define BVAL (1.0f/1024.0f)
#define NITER 10
#define IBLK 512           // iteration kernels: 512 blocks = 64 per batch
#define RPB  16            // rows per block

typedef __attribute__((ext_vector_type(8))) short bf16x8;
typedef __attribute__((ext_vector_type(4))) float f32x4;

__device__ inline unsigned short f2bf(float f) {
    __hip_bfloat16 h = __float2bfloat16(f);
    return __builtin_bit_cast(unsigned short, h);
}
__device__ inline float bf2f(unsigned short u) {
    unsigned int x = ((unsigned int)u) << 16;
    return __builtin_bit_cast(float, x);
}

// ---------------- init: zero part, out (slab/v fully written before first read)
__global__ __launch_bounds__(256) void init_bufs(float* partialB, float* out) {
    int i = threadIdx.x;
    if (i < B_) partialB[i] = 0.0f;
    if (i == 0) out[0] = 0.0f;
}

// ---------------- prep: row sumsq + bf16 cast. 192 thr = 768/4
__global__ __launch_bounds__(192) void prep_rows(const float* __restrict__ S, const float* __restrict__ T,
                                                 unsigned short* __restrict__ sbf, unsigned short* __restrict__ tbf,
                                                 float* __restrict__ sqS, float* __restrict__ sqT) {
    int bid = blockIdx.x;
    bool teach = bid >= B_*LS_;
    int row = teach ? bid - B_*LS_ : bid;
    const float* src = (teach ? T : S) + (size_t)row * D_;
    unsigned short* dst = (teach ? tbf : sbf) + (size_t)row * D_;
    int t = threadIdx.x;
    float4 v = *(const float4*)(src + t * 4);
    float ss = v.x*v.x + v.y*v.y + v.z*v.z + v.w*v.w;
    ushort4 o;
    o.x = f2bf(v.x); o.y = f2bf(v.y); o.z = f2bf(v.z); o.w = f2bf(v.w);
    *(ushort4*)(dst + t * 4) = o;
    for (int off = 32; off; off >>= 1) ss += __shfl_down(ss, off);
    __shared__ float red[3];
    int wid = t >> 6, lane = t & 63;
    if (lane == 0) red[wid] = ss;
    __syncthreads();
    if (t == 0) (teach ? sqT : sqS)[row] = red[0] + red[1] + red[2];
}

// ---------------- GEMM + cdist epilogue -> Kb = bf16(exp(-10C)), Cbm = bf16(C)
__device__ inline void gload_lds16(const void* g, void* l) {
    __builtin_amdgcn_global_load_lds((const __attribute__((address_space(1))) void*)g,
                                     (__attribute__((address_space(3))) void*)l, 16, 0, 0);
}

__global__ __launch_bounds__(256) void gemm_cdist(const unsigned short* __restrict__ S,
                                                  const unsigned short* __restrict__ T,
                                                  const float* __restrict__ sqS, const float* __restrict__ sqT,
                                                  unsigned short* __restrict__ Kb,
                                                  unsigned short* __restrict__ Cbm) {
    __shared__ unsigned short As[128 * 32];
    __shared__ unsigned short Bs[128 * 32];
    const int bid  = blockIdx.x;
    const int b    = bid & 7;
    const int tile = bid >> 3;
    const int brow = (tile >> 3) * 128;
    const int bcol = (tile & 7) * 128;
    const int tid  = threadIdx.x;
    const int wid  = tid >> 6, lane = tid & 63;
    const int wr = wid >> 1, wc = wid & 1;            // 2x2 waves, each 64x64
    const unsigned short* Sg = S + ((size_t)b * LS_ + brow) * D_;
    const unsigned short* Tg = T + ((size_t)b * LT_ + bcol) * D_;

    f32x4 acc[4][4] = {};
    const int r16 = lane & 15, kg = lane >> 4;

    for (int k0 = 0; k0 < D_; k0 += 32) {
        #pragma unroll
        for (int j = 0; j < 2; ++j) {
            int lin = j * 256 + tid;                  // 16B chunk id (512 per tile)
            int row = lin >> 2, c8 = (lin & 3) * 8;
            unsigned short* la = As + (size_t)(j * 256 + wid * 64) * 8;  // wave-uniform base
            unsigned short* lb = Bs + (size_t)(j * 256 + wid * 64) * 8;
            gload_lds16(Sg + (size_t)row * D_ + k0 + c8, la);
            gload_lds16(Tg + (size_t)row * D_ + k0 + c8, lb);
        }
        __syncthreads();
        bf16x8 af[4], bfr[4];
        #pragma unroll
        for (int f = 0; f < 4; ++f) {
            af[f]  = *(const bf16x8*)(As + (wr * 64 + f * 16 + r16) * 32 + kg * 8);
            bfr[f] = *(const bf16x8*)(Bs + (wc * 64 + f * 16 + r16) * 32 + kg * 8);
        }
        #pragma unroll
        for (int i = 0; i < 4; ++i)
            #pragma unroll
            for (int j = 0; j < 4; ++j)
                acc[i][j] = __builtin_amdgcn_mfma_f32_16x16x32_bf16(af[i], bfr[j], acc[i][j], 0, 0, 0);
        __syncthreads();
    }

    // epilogue: C/D map col=lane&15, row=(lane>>4)*4+reg
    #pragma unroll
    for (int i = 0; i < 4; ++i) {
        int gr0 = brow + wr * 64 + i * 16 + (lane >> 4) * 4;
        #pragma unroll
        for (int j = 0; j < 4; ++j) {
            int gc = bcol + wc * 64 + j * 16 + (lane & 15);
            float st = sqT[b * LT_ + gc];
            #pragma unroll
            for (int r = 0; r < 4; ++r) {
                float ss = sqS[b * LS_ + gr0 + r];
                float d2 = ss + st - 2.0f * acc[i][j][r];
                float c  = sqrtf(fmaxf(d2, 0.0f));
                size_t idx = ((size_t)b << 20) + (size_t)(gr0 + r) * LT_ + gc;
                Kb[idx]  = f2bf(__expf(-INV_REG * c));
                Cbm[idx] = f2bf(c);
            }
        }
    }
}

// ---------------- prepass: slab[b][blk][t] = sum_{s in block rows} K[s][t]  (u0 = 1)
// grid 512: b = bid&7, blk = bid>>3 (64/batch), 16 rows each; thread owns cols 4*tid..+3
__global__ __launch_bounds__(256) void prepass(const unsigned short* __restrict__ Kb,
                                               float* __restrict__ slab) {
    const int bid = blockIdx.x;
    const int b = bid & 7, blk = bid >> 3;
    const int s0 = blk * RPB;
    const int tid = threadIdx.x;
    const unsigned short* Kbat = Kb + ((size_t)b << 20);
    float a0 = 0.f, a1 = 0.f, a2 = 0.f, a3 = 0.f;
    #pragma unroll
    for (int r = 0; r < RPB; ++r) {
        ushort4 k4 = *(const ushort4*)(Kbat + ((size_t)(s0 + r) << 10) + tid * 4);
        a0 += bf2f(k4.x); a1 += bf2f(k4.y); a2 += bf2f(k4.z); a3 += bf2f(k4.w);
    }
    *(float4*)(slab + ((size_t)(b * 64 + blk) << 10) + tid * 4) = make_float4(a0, a1, a2, a3);
}

// ---------------- reduce_v: v[b][t] = BVAL / (sum_p slab[b][p][t] + EPS)
// grid 8 (one per batch), 256 thr, thread owns one float4 (4 cols)
__global__ __launch_bounds__(256) void reduce_v(const float* __restrict__ slab,
                                                float* __restrict__ v) {
    const int b = blockIdx.x;
    const int tid = threadIdx.x;
    const float* base = slab + ((size_t)(b * 64) << 10) + tid * 4;
    float4 acc = make_float4(0.f, 0.f, 0.f, 0.f);
    #pragma unroll 8
    for (int p = 0; p < 64; ++p) {
        float4 s = *(const float4*)(base + ((size_t)p << 10));
        acc.x += s.x; acc.y += s.y; acc.z += s.z; acc.w += s.w;
    }
    float4 o;
    o.x = BVAL / (acc.x + EPS_);
    o.y = BVAL / (acc.y + EPS_);
    o.z = BVAL / (acc.z + EPS_);
    o.w = BVAL / (acc.w + EPS_);
    *(float4*)(v + (b << 10) + tid * 4) = o;
}

// ---------------- sink_iter: phase A row-sums (u = AVAL/(K.v+eps)), phase B column partials (u.K)
// grid 512: b = bid&7, blk = bid>>3, rows s0..s0+15. Reads K once from L2/L3, no atomics.
__global__ __launch_bounds__(256) void sink_iter(const unsigned short* __restrict__ Kb,
                                                 const float* __restrict__ v,
                                                 float* __restrict__ slab) {
    const int bid = blockIdx.x;
    const int b = bid & 7, blk = bid >> 3;
    const int s0 = blk * RPB;
    const int tid = threadIdx.x;
    const int w = tid >> 6, lane = tid & 63;
    const int c4 = lane * 4;
    const unsigned short* Kbat = Kb + ((size_t)b << 20);
    const float* vb = v + (b << 10);
    __shared__ float ush[RPB];

    // phase A: wave w handles rows s0+w*4 .. +3
    float4 vq[4];
    #pragma unroll
    for (int q = 0; q < 4; ++q) vq[q] = *(const float4*)(vb + q * 256 + c4);
    #pragma unroll
    for (int rr = 0; rr < 4; ++rr) {
        int s = s0 + w * 4 + rr;
        const unsigned short* Kr = Kbat + ((size_t)s << 10);
        float acc = 0.f;
        #pragma unroll
        for (int q = 0; q < 4; ++q) {
            ushort4 k4 = *(const ushort4*)(Kr + q * 256 + c4);
            acc += bf2f(k4.x) * vq[q].x + bf2f(k4.y) * vq[q].y
                 + bf2f(k4.z) * vq[q].z + bf2f(k4.w) * vq[q].w;
        }
        for (int off = 32; off; off >>= 1) acc += __shfl_down(acc, off);
        if (lane == 0) ush[w * 4 + rr] = AVAL / (acc + EPS_);
    }
    __syncthreads();

    // phase B: thread owns cols 4*tid..+3 (K rows re-read from L2)
    float a0 = 0.f, a1 = 0.f, a2 = 0.f, a3 = 0.f;
    #pragma unroll
    for (int r = 0; r < RPB; ++r) {
        float u = ush[r];
        ushort4 k4 = *(const ushort4*)(Kbat + ((size_t)(s0 + r) << 10) + tid * 4);
        a0 += bf2f(k4.x) * u; a1 += bf2f(k4.y) * u;
        a2 += bf2f(k4.z) * u; a3 += bf2f(k4.w) * u;
    }
    *(float4*)(slab + ((size_t)(b * 64 + blk) << 10) + tid * 4) = make_float4(a0, a1, a2, a3);
}

// ---------------- final: u10 per row + loss partial in one pass (v = v9)
__global__ __launch_bounds__(256) void final_loss(const unsigned short* __restrict__ Kb,
                                                  const unsigned short* __restrict__ Cbm,
                                                  const float* __restrict__ v,
                                                  float* __restrict__ part) {
    const int bid = blockIdx.x;
    const int b = bid & 7, blk = bid >> 3;
    const int s0 = blk * RPB;
    const int tid = threadIdx.x;
    const int w = tid >> 6, lane = tid & 63;
    const int c4 = lane * 4;
    const unsigned short* Kbat = Kb + ((size_t)b << 20);
    const unsigned short* Cbat = Cbm + ((size_t)b << 20);
    const float* vb = v + (b << 10);

    float4 vq[4];
    #pragma unroll
    for (int q = 0; q < 4; ++q) vq[q] = *(const float4*)(vb + q * 256 + c4);
    float bacc = 0.f;
    #pragma unroll
    for (int rr = 0; rr < 4; ++rr) {
        int s = s0 + w * 4 + rr;
        const unsigned short* Kr = Kbat + ((size_t)s << 10);
        const unsigned short* Cr = Cbat + ((size_t)s << 10);
        float rk = 0.f, rkc = 0.f;
        #pragma unroll
        for (int q = 0; q < 4; ++q) {
            ushort4 k4 = *(const ushort4*)(Kr + q * 256 + c4);
            ushort4 cc = *(const ushort4*)(Cr + q * 256 + c4);
            float k0 = bf2f(k4.x) * vq[q].x, k1 = bf2f(k4.y) * vq[q].y;
            float k2 = bf2f(k4.z) * vq[q].z, k3 = bf2f(k4.w) * vq[q].w;
            rk  += k0 + k1 + k2 + k3;
            rkc += k0 * bf2f(cc.x) + k1 * bf2f(cc.y) + k2 * bf2f(cc.z) + k3 * bf2f(cc.w);
        }
        for (int off = 32; off; off >>= 1) {
            rk  += __shfl_down(rk, off);
            rkc += __shfl_down(rkc, off);
        }
        if (lane == 0) bacc += (AVAL / (rk + EPS_)) * rkc;
    }
    __shared__ float red[4];
    if (lane == 0) red[w] = bacc;
    __syncthreads();
    if (tid == 0) atomicAdd(&part[b], red[0] + red[1] + red[2] + red[3]);
}

__global__ void finalize(const float* __restrict__ partialB, float* __restrict__ out) {
    if (threadIdx.x == 0) {
        float s = 0.0f;
        for (int i = 0; i < B_; ++i) s += partialB[i];
        out[0] = s / (float)B_;
    }
}

extern "C" void kernel_launch(void* const* d_in, const int* in_sizes, int n_in,
                              void* d_out, int out_size, void* d_ws, size_t ws_size,
                              hipStream_t stream) {
    const float* S = (const float*)d_in[0];
    const float* T = (const float*)d_in[1];
    float* out = (float*)d_out;
    char* ws = (char*)d_ws;

    // workspace layout (bytes); total ~61 MB
    const size_t offKb   = 0;                                    // 16777216
    const size_t offCb   = offKb   + (size_t)B_*LS_*LT_*2;       // 16777216
    const size_t offSbf  = offCb   + (size_t)B_*LS_*LT_*2;       // 12582912
    const size_t offTbf  = offSbf  + (size_t)B_*LS_*D_*2;        // 12582912
    const size_t offSqS  = offTbf  + (size_t)B_*LT_*D_*2;
    const size_t offSqT  = offSqS  + (size_t)B_*LS_*4;
    const size_t offSlab = offSqT  + (size_t)B_*LT_*4;           // 512 slabs x 4KB = 2MB
    const size_t offV    = offSlab + (size_t)IBLK*LT_*4;         // 32KB
    const size_t offPart = offV    + (size_t)B_*LT_*4;
    const size_t need    = offPart + 64;
    if (ws_size < need) return;  // fail loudly rather than corrupt

    unsigned short* Kb  = (unsigned short*)(ws + offKb);
    unsigned short* Cbm = (unsigned short*)(ws + offCb);
    unsigned short* sbf = (unsigned short*)(ws + offSbf);
    unsigned short* tbf = (unsigned short*)(ws + offTbf);
    float* sqS  = (float*)(ws + offSqS);
    float* sqT  = (float*)(ws + offSqT);
    float* slab = (float*)(ws + offSlab);
    float* v    = (float*)(ws + offV);
    float* part = (float*)(ws + offPart);

    init_bufs<<<1, 256, 0, stream>>>(part, out);
    prep_rows<<<2 * B_ * LS_, 192, 0, stream>>>(S, T, sbf, tbf, sqS, sqT);
    gemm_cdist<<<512, 256, 0, stream>>>(sbf, tbf, sqS, sqT, Kb, Cbm);

    prepass<<<IBLK, 256, 0, stream>>>(Kb, slab);                 // denT_0 partials (u0 = 1)
    for (int i = 0; i < NITER - 1; ++i) {                        // 9 fused iterations
        reduce_v<<<B_, 256, 0, stream>>>(slab, v);               // v_i
        sink_iter<<<IBLK, 256, 0, stream>>>(Kb, v, slab);        // u_{i+1}, denT_{i+1} partials
    }
    reduce_v<<<B_, 256, 0, stream>>>(slab, v);                   // v_9
    final_loss<<<IBLK, 256, 0, stream>>>(Kb, Cbm, v, part);      // u_10 + loss
    finalize<<<1, 64, 0, stream>>>(part, out);
}

// Round 14
// 200.755 us; speedup vs baseline: 2.5129x; 1.0541x over previous
//
#include <hip/hip_runtime.h>
#include <hip/hip_bf16.h>

#define B_   8
#define LS_  1024
#define LT_  1024
#define D_   768
#define INV_REG 10.0f
#define EPS_ 1e-8f
#define AVAL (1.0f/1024.0f)
#define BVAL (1.0f/1024.0f)
#define NITER 10
#define IBLK 256           // iteration kernels: 256 blocks = 32 per batch (1/CU)
#define BPB  32            // blocks (and slabs) per batch
#define RPB  32            // rows per block

typedef __attribute__((ext_vector_type(8))) short bf16x8;
typedef __attribute__((ext_vector_type(4))) float f32x4;

__device__ inline unsigned short f2bf(float f) {
    __hip_bfloat16 h = __float2bfloat16(f);
    return __builtin_bit_cast(unsigned short, h);
}
__device__ inline float bf2f(unsigned short u) {
    unsigned int x = ((unsigned int)u) << 16;
    return __builtin_bit_cast(float, x);
}

// ---------------- prep: row sumsq + bf16 cast. 192 thr = 768/4
__global__ __launch_bounds__(192) void prep_rows(const float* __restrict__ S, const float* __restrict__ T,
                                                 unsigned short* __restrict__ sbf, unsigned short* __restrict__ tbf,
                                                 float* __restrict__ sqS, float* __restrict__ sqT) {
    int bid = blockIdx.x;
    bool teach = bid >= B_*LS_;
    int row = teach ? bid - B_*LS_ : bid;
    const float* src = (teach ? T : S) + (size_t)row * D_;
    unsigned short* dst = (teach ? tbf : sbf) + (size_t)row * D_;
    int t = threadIdx.x;
    float4 v = *(const float4*)(src + t * 4);
    float ss = v.x*v.x + v.y*v.y + v.z*v.z + v.w*v.w;
    ushort4 o;
    o.x = f2bf(v.x); o.y = f2bf(v.y); o.z = f2bf(v.z); o.w = f2bf(v.w);
    *(ushort4*)(dst + t * 4) = o;
    for (int off = 32; off; off >>= 1) ss += __shfl_down(ss, off);
    __shared__ float red[3];
    int wid = t >> 6, lane = t & 63;
    if (lane == 0) red[wid] = ss;
    __syncthreads();
    if (t == 0) (teach ? sqT : sqS)[row] = red[0] + red[1] + red[2];
}

// ---------------- GEMM + cdist epilogue -> Kb = bf16(exp(-10C)), Cbm = bf16(C)
__device__ inline void gload_lds16(const void* g, void* l) {
    __builtin_amdgcn_global_load_lds((const __attribute__((address_space(1))) void*)g,
                                     (__attribute__((address_space(3))) void*)l, 16, 0, 0);
}

__global__ __launch_bounds__(256) void gemm_cdist(const unsigned short* __restrict__ S,
                                                  const unsigned short* __restrict__ T,
                                                  const float* __restrict__ sqS, const float* __restrict__ sqT,
                                                  unsigned short* __restrict__ Kb,
                                                  unsigned short* __restrict__ Cbm) {
    __shared__ unsigned short As[128 * 32];
    __shared__ unsigned short Bs[128 * 32];
    const int bid  = blockIdx.x;
    const int b    = bid & 7;
    const int tile = bid >> 3;
    const int brow = (tile >> 3) * 128;
    const int bcol = (tile & 7) * 128;
    const int tid  = threadIdx.x;
    const int wid  = tid >> 6, lane = tid & 63;
    const int wr = wid >> 1, wc = wid & 1;            // 2x2 waves, each 64x64
    const unsigned short* Sg = S + ((size_t)b * LS_ + brow) * D_;
    const unsigned short* Tg = T + ((size_t)b * LT_ + bcol) * D_;

    f32x4 acc[4][4] = {};
    const int r16 = lane & 15, kg = lane >> 4;

    for (int k0 = 0; k0 < D_; k0 += 32) {
        #pragma unroll
        for (int j = 0; j < 2; ++j) {
            int lin = j * 256 + tid;                  // 16B chunk id (512 per tile)
            int row = lin >> 2, c8 = (lin & 3) * 8;
            unsigned short* la = As + (size_t)(j * 256 + wid * 64) * 8;  // wave-uniform base
            unsigned short* lb = Bs + (size_t)(j * 256 + wid * 64) * 8;
            gload_lds16(Sg + (size_t)row * D_ + k0 + c8, la);
            gload_lds16(Tg + (size_t)row * D_ + k0 + c8, lb);
        }
        __syncthreads();
        bf16x8 af[4], bfr[4];
        #pragma unroll
        for (int f = 0; f < 4; ++f) {
            af[f]  = *(const bf16x8*)(As + (wr * 64 + f * 16 + r16) * 32 + kg * 8);
            bfr[f] = *(const bf16x8*)(Bs + (wc * 64 + f * 16 + r16) * 32 + kg * 8);
        }
        #pragma unroll
        for (int i = 0; i < 4; ++i)
            #pragma unroll
            for (int j = 0; j < 4; ++j)
                acc[i][j] = __builtin_amdgcn_mfma_f32_16x16x32_bf16(af[i], bfr[j], acc[i][j], 0, 0, 0);
        __syncthreads();
    }

    // epilogue: C/D map col=lane&15, row=(lane>>4)*4+reg
    #pragma unroll
    for (int i = 0; i < 4; ++i) {
        int gr0 = brow + wr * 64 + i * 16 + (lane >> 4) * 4;
        #pragma unroll
        for (int j = 0; j < 4; ++j) {
            int gc = bcol + wc * 64 + j * 16 + (lane & 15);
            float st = sqT[b * LT_ + gc];
            #pragma unroll
            for (int r = 0; r < 4; ++r) {
                float ss = sqS[b * LS_ + gr0 + r];
                float d2 = ss + st - 2.0f * acc[i][j][r];
                float c  = sqrtf(fmaxf(d2, 0.0f));
                size_t idx = ((size_t)b << 20) + (size_t)(gr0 + r) * LT_ + gc;
                Kb[idx]  = f2bf(__expf(-INV_REG * c));
                Cbm[idx] = f2bf(c);
            }
        }
    }
}

// ---------------- prepass: slab[b][blk][t] = sum_{s in block rows} K[s][t]  (u0 = 1)
__global__ __launch_bounds__(256) void prepass(const unsigned short* __restrict__ Kb,
                                               float* __restrict__ slab) {
    const int bid = blockIdx.x;
    const int b = bid & 7, blk = bid >> 3;
    const int s0 = blk * RPB;
    const int tid = threadIdx.x;
    const unsigned short* Kbat = Kb + ((size_t)b << 20);
    float a0 = 0.f, a1 = 0.f, a2 = 0.f, a3 = 0.f;
    #pragma unroll 8
    for (int r = 0; r < RPB; ++r) {
        ushort4 k4 = *(const ushort4*)(Kbat + ((size_t)(s0 + r) << 10) + tid * 4);
        a0 += bf2f(k4.x); a1 += bf2f(k4.y); a2 += bf2f(k4.z); a3 += bf2f(k4.w);
    }
    *(float4*)(slab + ((size_t)(b * BPB + blk) << 10) + tid * 4) = make_float4(a0, a1, a2, a3);
}

// ---------------- sink_iter: phase0 reduce src slabs -> v (LDS); A: u rows; B: column partials -> dst
// grid 256: b = bid&7, blk = bid>>3, rows s0..s0+31. No atomics; src/dst double-buffered.
__global__ __launch_bounds__(256) void sink_iter(const unsigned short* __restrict__ Kb,
                                                 const float* __restrict__ src,
                                                 float* __restrict__ dst) {
    const int bid = blockIdx.x;
    const int b = bid & 7, blk = bid >> 3;
    const int s0 = blk * RPB;
    const int tid = threadIdx.x;
    const int w = tid >> 6, lane = tid & 63;
    const int c4 = lane * 4;
    const unsigned short* Kbat = Kb + ((size_t)b << 20);
    __shared__ float v_lds[1024];
    __shared__ float ush[RPB];

    // phase 0: thread reduces cols 4*tid..+3 over the 32 slabs of batch b
    {
        const float* base = src + ((size_t)(b * BPB) << 10) + tid * 4;
        float4 acc = make_float4(0.f, 0.f, 0.f, 0.f);
        #pragma unroll 8
        for (int p = 0; p < BPB; ++p) {
            float4 s = *(const float4*)(base + ((size_t)p << 10));
            acc.x += s.x; acc.y += s.y; acc.z += s.z; acc.w += s.w;
        }
        v_lds[tid * 4 + 0] = BVAL / (acc.x + EPS_);
        v_lds[tid * 4 + 1] = BVAL / (acc.y + EPS_);
        v_lds[tid * 4 + 2] = BVAL / (acc.z + EPS_);
        v_lds[tid * 4 + 3] = BVAL / (acc.w + EPS_);
    }
    __syncthreads();

    // phase A: wave w handles rows s0 + w*8 .. +7 ; u = AVAL/(K.v+eps)
    float4 vq[4];
    #pragma unroll
    for (int q = 0; q < 4; ++q) vq[q] = *(const float4*)&v_lds[q * 256 + c4];
    #pragma unroll
    for (int rr = 0; rr < 8; ++rr) {
        int s = s0 + w * 8 + rr;
        const unsigned short* Kr = Kbat + ((size_t)s << 10);
        float acc = 0.f;
        #pragma unroll
        for (int q = 0; q < 4; ++q) {
            ushort4 k4 = *(const ushort4*)(Kr + q * 256 + c4);
            acc += bf2f(k4.x) * vq[q].x + bf2f(k4.y) * vq[q].y
                 + bf2f(k4.z) * vq[q].z + bf2f(k4.w) * vq[q].w;
        }
        for (int off = 32; off; off >>= 1) acc += __shfl_down(acc, off);
        if (lane == 0) ush[w * 8 + rr] = AVAL / (acc + EPS_);
    }
    __syncthreads();

    // phase B: thread owns cols 4*tid..+3; dst slab = sum_s u_s K[s][cols]
    float a0 = 0.f, a1 = 0.f, a2 = 0.f, a3 = 0.f;
    #pragma unroll 8
    for (int r = 0; r < RPB; ++r) {
        float u = ush[r];
        ushort4 k4 = *(const ushort4*)(Kbat + ((size_t)(s0 + r) << 10) + tid * 4);
        a0 += bf2f(k4.x) * u; a1 += bf2f(k4.y) * u;
        a2 += bf2f(k4.z) * u; a3 += bf2f(k4.w) * u;
    }
    *(float4*)(dst + ((size_t)(b * BPB + blk) << 10) + tid * 4) = make_float4(a0, a1, a2, a3);
}

// ---------------- final: phase0 reduce -> v10; per-row u10 + loss partial; plain store per block
__global__ __launch_bounds__(256) void final_loss(const unsigned short* __restrict__ Kb,
                                                  const unsigned short* __restrict__ Cbm,
                                                  const float* __restrict__ src,
                                                  float* __restrict__ partial) {
    const int bid = blockIdx.x;
    const int b = bid & 7, blk = bid >> 3;
    const int s0 = blk * RPB;
    const int tid = threadIdx.x;
    const int w = tid >> 6, lane = tid & 63;
    const int c4 = lane * 4;
    const unsigned short* Kbat = Kb + ((size_t)b << 20);
    const unsigned short* Cbat = Cbm + ((size_t)b << 20);
    __shared__ float v_lds[1024];

    {
        const float* base = src + ((size_t)(b * BPB) << 10) + tid * 4;
        float4 acc = make_float4(0.f, 0.f, 0.f, 0.f);
        #pragma unroll 8
        for (int p = 0; p < BPB; ++p) {
            float4 s = *(const float4*)(base + ((size_t)p << 10));
            acc.x += s.x; acc.y += s.y; acc.z += s.z; acc.w += s.w;
        }
        v_lds[tid * 4 + 0] = BVAL / (acc.x + EPS_);
        v_lds[tid * 4 + 1] = BVAL / (acc.y + EPS_);
        v_lds[tid * 4 + 2] = BVAL / (acc.z + EPS_);
        v_lds[tid * 4 + 3] = BVAL / (acc.w + EPS_);
    }
    __syncthreads();

    float4 vq[4];
    #pragma unroll
    for (int q = 0; q < 4; ++q) vq[q] = *(const float4*)&v_lds[q * 256 + c4];
    float bacc = 0.f;
    #pragma unroll
    for (int rr = 0; rr < 8; ++rr) {
        int s = s0 + w * 8 + rr;
        const unsigned short* Kr = Kbat + ((size_t)s << 10);
        const unsigned short* Cr = Cbat + ((size_t)s << 10);
        float rk = 0.f, rkc = 0.f;
        #pragma unroll
        for (int q = 0; q < 4; ++q) {
            ushort4 k4 = *(const ushort4*)(Kr + q * 256 + c4);
            ushort4 cc = *(const ushort4*)(Cr + q * 256 + c4);
            float k0 = bf2f(k4.x) * vq[q].x, k1 = bf2f(k4.y) * vq[q].y;
            float k2 = bf2f(k4.z) * vq[q].z, k3 = bf2f(k4.w) * vq[q].w;
            rk  += k0 + k1 + k2 + k3;
            rkc += k0 * bf2f(cc.x) + k1 * bf2f(cc.y) + k2 * bf2f(cc.z) + k3 * bf2f(cc.w);
        }
        for (int off = 32; off; off >>= 1) {
            rk  += __shfl_down(rk, off);
            rkc += __shfl_down(rkc, off);
        }
        if (lane == 0) bacc += (AVAL / (rk + EPS_)) * rkc;
    }
    __shared__ float red[4];
    if (lane == 0) red[w] = bacc;
    __syncthreads();
    if (tid == 0) partial[bid] = red[0] + red[1] + red[2] + red[3];
}

// ---------------- finalize: sum 256 per-block partials; mean over batches = total/8
__global__ __launch_bounds__(256) void finalize(const float* __restrict__ partial, float* __restrict__ out) {
    int tid = threadIdx.x;
    float x = partial[tid];
    for (int off = 32; off; off >>= 1) x += __shfl_down(x, off);
    __shared__ float red[4];
    int w = tid >> 6, lane = tid & 63;
    if (lane == 0) red[w] = x;
    __syncthreads();
    if (tid == 0) out[0] = (red[0] + red[1] + red[2] + red[3]) / (float)B_;
}

extern "C" void kernel_launch(void* const* d_in, const int* in_sizes, int n_in,
                              void* d_out, int out_size, void* d_ws, size_t ws_size,
                              hipStream_t stream) {
    const float* S = (const float*)d_in[0];
    const float* T = (const float*)d_in[1];
    float* out = (float*)d_out;
    char* ws = (char*)d_ws;

    // workspace layout (bytes); total ~61 MB
    const size_t offKb   = 0;                                    // 16777216
    const size_t offCb   = offKb   + (size_t)B_*LS_*LT_*2;       // 16777216
    const size_t offSbf  = offCb   + (size_t)B_*LS_*LT_*2;       // 12582912
    const size_t offTbf  = offSbf  + (size_t)B_*LS_*D_*2;        // 12582912
    const size_t offSqS  = offTbf  + (size_t)B_*LT_*D_*2;
    const size_t offSqT  = offSqS  + (size_t)B_*LS_*4;
    const size_t offSlabA= offSqT  + (size_t)B_*LT_*4;           // 256 x 4KB = 1MB
    const size_t offSlabB= offSlabA+ (size_t)IBLK*LT_*4;         // 1MB
    const size_t offPart = offSlabB+ (size_t)IBLK*LT_*4;         // 256 f32
    const size_t need    = offPart + IBLK*4;
    if (ws_size < need) return;  // fail loudly rather than corrupt

    unsigned short* Kb  = (unsigned short*)(ws + offKb);
    unsigned short* Cbm = (unsigned short*)(ws + offCb);
    unsigned short* sbf = (unsigned short*)(ws + offSbf);
    unsigned short* tbf = (unsigned short*)(ws + offTbf);
    float* sqS  = (float*)(ws + offSqS);
    float* sqT  = (float*)(ws + offSqT);
    float* slabA= (float*)(ws + offSlabA);
    float* slabB= (float*)(ws + offSlabB);
    float* part = (float*)(ws + offPart);

    prep_rows<<<2 * B_ * LS_, 192, 0, stream>>>(S, T, sbf, tbf, sqS, sqT);
    gemm_cdist<<<512, 256, 0, stream>>>(sbf, tbf, sqS, sqT, Kb, Cbm);

    prepass<<<IBLK, 256, 0, stream>>>(Kb, slabA);                // K^T u0 partials (u0 = 1)
    float* cur = slabA; float* nxt = slabB;
    for (int i = 0; i < NITER - 1; ++i) {                        // 9 fused iterations
        sink_iter<<<IBLK, 256, 0, stream>>>(Kb, cur, nxt);       // v_i+1 (in-block), u_i+1, K^T u partials
        float* t2 = cur; cur = nxt; nxt = t2;
    }
    final_loss<<<IBLK, 256, 0, stream>>>(Kb, Cbm, cur, part);    // v_10, u_10, loss partials
    finalize<<<1, IBLK, 0, stream>>>(part, out);
}